// Round 11
// baseline (43.265 us; speedup 1.0000x reference)
//
#include <hip/hip_runtime.h>

#define SS 4096
#define DD 1024
#define EE 128
#define SCALE 0.08838834764831845f   // 1/sqrt(128)

typedef __bf16 bf16x8 __attribute__((ext_vector_type(8)));
typedef float  f32x4  __attribute__((ext_vector_type(4)));

__device__ __forceinline__ void gload16(const void* g, void* l) {
  __builtin_amdgcn_global_load_lds(
      (const __attribute__((address_space(1))) void*)g,
      (__attribute__((address_space(3))) void*)l, 16, 0, 0);
}

// ---------------------------------------------------------------------------
// K0: cast x (8192x1024) AND W (q|k|v 384x1024) fp32 -> bf16.
// grid 2144: blocks 0-2047 -> x, 2048-2143 -> W.  4096 elems/block.
// ---------------------------------------------------------------------------
__global__ __launch_bounds__(256) void cast_kernel(
    const float* __restrict__ x,  const float* __restrict__ qW,
    const float* __restrict__ kW, const float* __restrict__ vW,
    __bf16* __restrict__ xb, __bf16* __restrict__ Wb)
{
  const int blk = blockIdx.x, tid = threadIdx.x;
  const float* src;
  __bf16* dst;
  size_t base;
  if (blk < 2048) { src = x; dst = xb; base = (size_t)blk * 4096; }
  else {
    int wb2 = blk - 2048;                // 0..95
    int m = wb2 >> 5;                    // 0..2
    src = (m == 0) ? qW : (m == 1 ? kW : vW);
    dst = Wb + (size_t)m * EE * DD;
    base = (size_t)(wb2 & 31) * 4096;
  }
  #pragma unroll
  for (int j = 0; j < 2; ++j) {
    size_t o = base + (size_t)j * 2048 + (size_t)tid * 8;
    float4 u0 = *(const float4*)&src[o];
    float4 u1 = *(const float4*)&src[o + 4];
    bf16x8 v = { (__bf16)u0.x, (__bf16)u0.y, (__bf16)u0.z, (__bf16)u0.w,
                 (__bf16)u1.x, (__bf16)u1.y, (__bf16)u1.z, (__bf16)u1.w };
    *(bf16x8*)&dst[o] = v;
  }
}

// ---------------------------------------------------------------------------
// K1: fused QKV projection, all-bf16.  BM=64 BN=64 BK=64; grid 768
// (3 blocks/CU, 12 waves/CU), 256 thr (4 waves 2x2, wave 32x32).
// Both A and B staged via source-swizzled global_load_lds (2 instr each per
// wave per tile), double-buffered, simple 2-phase loop (R8-proven).
// Per wave-K-step: 4 gload + 8 ds_read_b128 + 8 MFMA.
// ctile 0,1 -> Q (+bias, *SCALE, row-major); 2,3 -> KT; 4,5 -> VT.
// ---------------------------------------------------------------------------
__global__ __launch_bounds__(256) void proj_kernel(
    const __bf16* __restrict__ xb, const __bf16* __restrict__ Wb,
    const float* __restrict__ qB, const float* __restrict__ kB,
    const float* __restrict__ vB,
    __bf16* __restrict__ Qbf, __bf16* __restrict__ KT, __bf16* __restrict__ VT)
{
  __shared__ __attribute__((aligned(16))) __bf16 ldsA[2][64 * 64];  // 16 KB
  __shared__ __attribute__((aligned(16))) __bf16 ldsB[2][64 * 64];  // 16 KB

  const int tid  = threadIdx.x;
  const int w    = tid >> 6, lane = tid & 63;
  const int l15  = lane & 15, l4 = lane >> 4;
  const int wr   = w >> 1, wc = w & 1;          // wave tile 32r x 32c

  // XCD-chunked bijective swizzle (768 % 8 == 0), rtile-major within XCD
  const int id   = blockIdx.x;
  const int swz  = (id & 7) * 96 + (id >> 3);
  const int rt   = swz / 6, ct = swz % 6;
  const int row0 = rt * 64;                     // flat row [0,8192)
  const int g0   = ct * 64;                     // col base [0,384)

  // staging: instr covers 8 rows x 64 bf16; dest row = base8 + (lane>>3),
  // dest chunk = lane&7; r&7 = lane>>3 -> src chunk = (lane&7)^(lane>>3).
  const int sRow = lane >> 3;                   // 0..7
  const int sChk = (lane & 7) ^ sRow;           // source-swizzled 16B chunk
  const __bf16* gA = xb + (size_t)(row0 + w * 16 + sRow) * DD + sChk * 8;
  const __bf16* gB = Wb + (size_t)(g0   + w * 16 + sRow) * DD + sChk * 8;

  f32x4 acc[2][2] = {};

#define STAGE(P, T) {                                                        \
    const int k0_ = (T) * 64;                                                \
    gload16(gA + k0_,                   &ldsA[P][(w * 16    ) * 64]);        \
    gload16(gA + k0_ + (size_t)8 * DD,  &ldsA[P][(w * 16 + 8) * 64]);        \
    gload16(gB + k0_,                   &ldsB[P][(w * 16    ) * 64]);        \
    gload16(gB + k0_ + (size_t)8 * DD,  &ldsB[P][(w * 16 + 8) * 64]);        }

#define COMPUTE(P) {                                                         \
    const int rs7 = l15 & 7;                                                 \
    _Pragma("unroll") for (int ks = 0; ks < 2; ++ks) {                       \
      const int so = ((ks * 4 + l4) ^ rs7) << 3;                             \
      bf16x8 a0 = *(const bf16x8*)&ldsA[P][(wr * 32      + l15) * 64 + so];  \
      bf16x8 a1 = *(const bf16x8*)&ldsA[P][(wr * 32 + 16 + l15) * 64 + so];  \
      bf16x8 b0 = *(const bf16x8*)&ldsB[P][(wc * 32      + l15) * 64 + so];  \
      bf16x8 b1 = *(const bf16x8*)&ldsB[P][(wc * 32 + 16 + l15) * 64 + so];  \
      acc[0][0] = __builtin_amdgcn_mfma_f32_16x16x32_bf16(a0,b0,acc[0][0],0,0,0); \
      acc[0][1] = __builtin_amdgcn_mfma_f32_16x16x32_bf16(a0,b1,acc[0][1],0,0,0); \
      acc[1][0] = __builtin_amdgcn_mfma_f32_16x16x32_bf16(a1,b0,acc[1][0],0,0,0); \
      acc[1][1] = __builtin_amdgcn_mfma_f32_16x16x32_bf16(a1,b1,acc[1][1],0,0,0); \
    } }

  STAGE(0, 0);
  __syncthreads();
  for (int t = 0; t < 15; ++t) {
    STAGE((t + 1) & 1, t + 1);
    COMPUTE(t & 1);
    __syncthreads();
  }
  COMPUTE(1);
  __syncthreads();
#undef STAGE
#undef COMPUTE

  const float* bias = (g0 < 128) ? qB : (g0 < 256 ? kB : vB);
  const int bofs = (g0 < 128) ? g0 : (g0 < 256 ? g0 - 128 : g0 - 256);

  if (ct < 2) {                                  // Q: row-major, *SCALE folded
    #pragma unroll
    for (int m = 0; m < 2; ++m)
      #pragma unroll
      for (int n = 0; n < 2; ++n) {
        const int col = wc * 32 + n * 16 + l15;
        const float bv = bias[bofs + col];
        #pragma unroll
        for (int r = 0; r < 4; ++r) {
          const int row = row0 + wr * 32 + m * 16 + l4 * 4 + r;
          Qbf[(size_t)row * EE + g0 + col] =
              (__bf16)((acc[m][n][r] + bv) * SCALE);
        }
      }
  } else {                                       // K/V: transpose via LDS
    __bf16* Tb = (__bf16*)ldsA;                  // [64 cols][64 rows chunkXOR]
    #pragma unroll
    for (int m = 0; m < 2; ++m)
      #pragma unroll
      for (int n = 0; n < 2; ++n) {
        const int tc = wc * 32 + n * 16 + l15;
        const float bv = bias[bofs + tc];
        #pragma unroll
        for (int r = 0; r < 4; ++r) {
          const int rl = wr * 32 + m * 16 + l4 * 4 + r;
          Tb[tc * 64 + (((rl >> 3) ^ (tc & 7)) << 3) + (rl & 7)] =
              (__bf16)(acc[m][n][r] + bv);
        }
      }
    __syncthreads();
    const int col = tid >> 2, p2 = tid & 3;      // 64 cols x 4 thr
    const int b = row0 >> 12, s0 = row0 & 4095;
    __bf16* dst = (ct < 4)
        ? &KT[((size_t)b * EE + (ct - 2) * 64 + col) * SS + s0]
        : &VT[((size_t)b * EE + (ct - 4) * 64 + col) * SS + s0];
    #pragma unroll
    for (int j = 0; j < 2; ++j) {
      const int ch = p2 * 2 + j;                 // 8 chunks of 8 bf16
      bf16x8 v = *(const bf16x8*)&Tb[col * 64 + ((ch ^ (col & 7)) << 3)];
      *(bf16x8*)&dst[ch * 8] = v;
    }
  }
}

// ---------------------------------------------------------------------------
// K2: partial K^T V.  grid (64 s-chunks, 2 f-halves, 2 b) x 256 thr.
// ---------------------------------------------------------------------------
__global__ __launch_bounds__(256) void ktv_kernel(
    const __bf16* __restrict__ KT, const __bf16* __restrict__ VT,
    float* __restrict__ part)
{
  const int c = blockIdx.x, fh = blockIdx.y, b = blockIdx.z;
  const int tid = threadIdx.x;
  const int w = tid >> 6, lane = tid & 63;
  const int l15 = lane & 15, l4 = lane >> 4;
  const int s0 = c * 64;
  const int fbase = fh * 64 + w * 16;
  const __bf16* Kb = KT + (size_t)b * EE * SS;
  const __bf16* Vb = VT + (size_t)b * EE * SS;

  f32x4 acc[8] = {};
  #pragma unroll
  for (int ks = 0; ks < 2; ++ks) {
    const int s = s0 + ks * 32 + 8 * l4;
    bf16x8 bv = *(const bf16x8*)&Vb[(size_t)(fbase + l15) * SS + s];
    #pragma unroll
    for (int i = 0; i < 8; ++i) {
      bf16x8 av = *(const bf16x8*)&Kb[(size_t)(i * 16 + l15) * SS + s];
      acc[i] = __builtin_amdgcn_mfma_f32_16x16x32_bf16(av, bv, acc[i], 0, 0, 0);
    }
  }
  float* P = part + (size_t)(b * 64 + c) * 16384;
  #pragma unroll
  for (int i = 0; i < 8; ++i)
    #pragma unroll
    for (int r = 0; r < 4; ++r) {
      int e = i * 16 + l4 * 4 + r;
      int f = fbase + l15;
      P[e * 128 + f] = acc[i][r];
    }
}

// ---------------------------------------------------------------------------
// K3: reduce 64 partials -> MT[b][f][e] = sum (scale folded into Qbf).
// ---------------------------------------------------------------------------
__global__ __launch_bounds__(256) void reduce_kernel(
    const float* __restrict__ part, __bf16* __restrict__ MT)
{
  const int b = blockIdx.y;
  const int e = blockIdx.x * 2 + (threadIdx.x >> 7);
  const int f = threadIdx.x & 127;
  float s = 0.f;
  for (int cc = 0; cc < 64; ++cc)
    s += part[(size_t)(b * 64 + cc) * 16384 + e * 128 + f];
  MT[((size_t)b * EE + f) * EE + e] = (__bf16)s;
}

// ---------------------------------------------------------------------------
// K4: O = Q * M  (MT[f][e]).  grid (128, 2) x 128 thr.
// ---------------------------------------------------------------------------
__global__ __launch_bounds__(128) void qm_kernel(
    const __bf16* __restrict__ Qbf, const __bf16* __restrict__ MT,
    float* __restrict__ out)
{
  const int b = blockIdx.y;
  const int tid = threadIdx.x;
  const int w = tid >> 6, lane = tid & 63;
  const int l15 = lane & 15, l4 = lane >> 4;
  const int row0 = blockIdx.x * 32 + w * 16;
  const __bf16* Qb = Qbf + (size_t)b * SS * EE;
  const __bf16* Mb = MT + (size_t)b * EE * EE;

  f32x4 acc[8] = {};
  #pragma unroll
  for (int ks = 0; ks < 4; ++ks) {
    const int e = ks * 32 + 8 * l4;
    bf16x8 av = *(const bf16x8*)&Qb[(size_t)(row0 + l15) * EE + e];
    #pragma unroll
    for (int j = 0; j < 8; ++j) {
      bf16x8 bv = *(const bf16x8*)&Mb[(size_t)(j * 16 + l15) * EE + e];
      acc[j] = __builtin_amdgcn_mfma_f32_16x16x32_bf16(av, bv, acc[j], 0, 0, 0);
    }
  }
  #pragma unroll
  for (int j = 0; j < 8; ++j)
    #pragma unroll
    for (int r = 0; r < 4; ++r) {
      int srow = row0 + l4 * 4 + r;
      int f = j * 16 + l15;
      out[((size_t)b * SS + srow) * EE + f] = acc[j][r];
    }
}

extern "C" void kernel_launch(void* const* d_in, const int* in_sizes, int n_in,
                              void* d_out, int out_size, void* d_ws, size_t ws_size,
                              hipStream_t stream) {
  const float* x  = (const float*)d_in[0];
  const float* qW = (const float*)d_in[1];
  const float* qB = (const float*)d_in[2];
  const float* kW = (const float*)d_in[3];
  const float* kB = (const float*)d_in[4];
  const float* vW = (const float*)d_in[5];
  const float* vB = (const float*)d_in[6];
  float* out = (float*)d_out;

  char* base = (char*)d_ws;
  __bf16* xb  = (__bf16*)(base);                         // 16 MB
  __bf16* Wb  = (__bf16*)(base + (16u << 20));           // 768 KB
  __bf16* Qbf = (__bf16*)(base + (17u << 20));           // 2 MB
  __bf16* KT  = (__bf16*)(base + (19u << 20));           // 2 MB
  __bf16* VT  = (__bf16*)(base + (21u << 20));           // 2 MB
  float*  part= (float*) (base + (23u << 20));           // 8 MB
  __bf16* MT  = (__bf16*)(base + (31u << 20));           // 64 KB

  cast_kernel  <<<dim3(2144),     256, 0, stream>>>(x, qW, kW, vW, xb, Wb);
  proj_kernel  <<<dim3(768),      256, 0, stream>>>(xb, Wb, qB, kB, vB, Qbf, KT, VT);
  ktv_kernel   <<<dim3(64, 2, 2), 256, 0, stream>>>(KT, VT, part);
  reduce_kernel<<<dim3(64, 2),    256, 0, stream>>>(part, MT);
  qm_kernel    <<<dim3(128, 2),   128, 0, stream>>>(Qbf, MT, out);
}

// Round 13
// 43.221 us; speedup vs baseline: 1.0010x; 1.0010x over previous
//
#include <hip/hip_runtime.h>

#define SS 4096
#define DD 1024
#define EE 128
#define SCALE 0.08838834764831845f   // 1/sqrt(128)

typedef __bf16 bf16x8 __attribute__((ext_vector_type(8)));
typedef float  f32x4  __attribute__((ext_vector_type(4)));

__device__ __forceinline__ void gload16(const void* g, void* l) {
  __builtin_amdgcn_global_load_lds(
      (const __attribute__((address_space(1))) void*)g,
      (__attribute__((address_space(3))) void*)l, 16, 0, 0);
}

// ---------------------------------------------------------------------------
// K1: fused QKV projection, absorbs both casts.  BM=64 BN=64 BK=64;
// grid 768 (3 blocks/CU, 12 waves/CU), 256 thr (4 waves 2x2, wave 32x32).
// A: x fp32 via source-swizzled global_load_lds into fp32 LDS (R7-proven),
//    cvt on read.  B: W fp32 reg-staged, load-early/COMPUTE/cvt+write-late
//    (T14), XOR-swizzled ds_write (R8-proven).
// ctile 0,1 -> Q (+bias, *SCALE, row-major); 2,3 -> KT; 4,5 -> VT.
// ---------------------------------------------------------------------------
__global__ __launch_bounds__(256, 3) void proj_kernel(
    const float* __restrict__ x,
    const float* __restrict__ qW, const float* __restrict__ qB,
    const float* __restrict__ kW, const float* __restrict__ kB,
    const float* __restrict__ vW, const float* __restrict__ vB,
    __bf16* __restrict__ Qbf, __bf16* __restrict__ KT, __bf16* __restrict__ VT)
{
  __shared__ __attribute__((aligned(16))) float  ldsA[2][64 * 64];  // 32 KB
  __shared__ __attribute__((aligned(16))) __bf16 ldsB[2][64 * 64];  // 16 KB

  const int tid  = threadIdx.x;
  const int w    = tid >> 6, lane = tid & 63;
  const int l15  = lane & 15, l4 = lane >> 4;
  const int wr   = w >> 1, wc = w & 1;          // wave tile 32r x 32c

  // XCD-chunked bijective swizzle (768 % 8 == 0), rtile-major within XCD
  const int id   = blockIdx.x;
  const int swz  = (id & 7) * 96 + (id >> 3);
  const int rt   = swz / 6, ct = swz % 6;
  const int row0 = rt * 64;                     // flat row [0,8192)
  const int g0   = ct * 64;                     // col base [0,384)

  const float* __restrict__ Wsel = (ct < 2) ? qW : (ct < 4 ? kW : vW);
  const float* __restrict__ bias = (ct < 2) ? qB : (ct < 4 ? kB : vB);
  const int bofs = (ct < 2) ? g0 : (ct < 4 ? g0 - 128 : g0 - 256);

  // ---- A staging (fp32 gload16, source-swizzled; R7-proven) ----
  // wave w, instr j: rows w*16 + j*4 + aRow; r&7 = (j&1)*4 + aRow.
  const int aRow = lane >> 4;                   // 0..3
  const int aPos = lane & 15;
  const int cE   = aPos ^ aRow;                 // j even
  const int cO   = aPos ^ (4 | aRow);           // j odd
  const float* gAe = x + (size_t)(row0 + w * 16 + aRow) * DD + cE * 4;
  const float* gAo = x + (size_t)(row0 + w * 16 + aRow) * DD + cO * 4;

  // ---- B reg-staging: thread -> (row=tid>>2 of 64 cols, seg=tid&3) ----
  const int brow = tid >> 2;                    // ldsB row = output col
  const int bseg = tid & 3;                     // 16 floats at k = bseg*16
  const int brs  = brow & 7;
  const float* gBW = Wsel + (size_t)(bofs + brow) * DD + bseg * 16;

  f32x4 acc[2][2] = {};
  f32x4 rB[4];

#define BLOAD(T) {                                                           \
    const float* g_ = gBW + (T) * 64;                                        \
    rB[0] = *(const f32x4*)(g_);      rB[1] = *(const f32x4*)(g_ + 4);       \
    rB[2] = *(const f32x4*)(g_ + 8);  rB[3] = *(const f32x4*)(g_ + 12); }

#define BWRITE(P) {                                                          \
    bf16x8 v0_ = { (__bf16)rB[0][0], (__bf16)rB[0][1], (__bf16)rB[0][2],     \
                   (__bf16)rB[0][3], (__bf16)rB[1][0], (__bf16)rB[1][1],     \
                   (__bf16)rB[1][2], (__bf16)rB[1][3] };                     \
    bf16x8 v1_ = { (__bf16)rB[2][0], (__bf16)rB[2][1], (__bf16)rB[2][2],     \
                   (__bf16)rB[2][3], (__bf16)rB[3][0], (__bf16)rB[3][1],     \
                   (__bf16)rB[3][2], (__bf16)rB[3][3] };                     \
    *(bf16x8*)&ldsB[P][brow * 64 + (((bseg * 2)     ^ brs) << 3)] = v0_;     \
    *(bf16x8*)&ldsB[P][brow * 64 + (((bseg * 2 + 1) ^ brs) << 3)] = v1_; }

#define ASTAGE(P, T) {                                                       \
    const int k0_ = (T) * 64;                                                \
    gload16(gAe + k0_,                    &ldsA[P][(w * 16 +  0) * 64]);     \
    gload16(gAo + k0_ + (size_t) 4 * DD,  &ldsA[P][(w * 16 +  4) * 64]);     \
    gload16(gAe + k0_ + (size_t) 8 * DD,  &ldsA[P][(w * 16 +  8) * 64]);     \
    gload16(gAo + k0_ + (size_t)12 * DD,  &ldsA[P][(w * 16 + 12) * 64]);     }

#define CVT8(LO, HI) (bf16x8){ (__bf16)(LO)[0], (__bf16)(LO)[1],             \
    (__bf16)(LO)[2], (__bf16)(LO)[3], (__bf16)(HI)[0], (__bf16)(HI)[1],      \
    (__bf16)(HI)[2], (__bf16)(HI)[3] }

#define COMPUTE(P) {                                                         \
    const int rs7 = l15 & 7;                                                 \
    _Pragma("unroll") for (int ks = 0; ks < 2; ++ks) {                       \
      bf16x8 af[2], bq[2];                                                   \
      _Pragma("unroll") for (int m = 0; m < 2; ++m) {                        \
        const int row = wr * 32 + m * 16 + l15;                              \
        const int c0 = ks * 8 + l4 * 2;                                      \
        f32x4 lo = *(const f32x4*)&ldsA[P][row * 64 + (( c0      ^ rs7) << 2)]; \
        f32x4 hi = *(const f32x4*)&ldsA[P][row * 64 + (((c0 + 1) ^ rs7) << 2)]; \
        af[m] = CVT8(lo, hi);                                                \
      }                                                                      \
      _Pragma("unroll") for (int n = 0; n < 2; ++n) {                        \
        const int row = wc * 32 + n * 16 + l15;                              \
        bq[n] = *(const bf16x8*)&ldsB[P][row * 64 + (((ks*4 + l4) ^ rs7) << 3)]; \
      }                                                                      \
      acc[0][0] = __builtin_amdgcn_mfma_f32_16x16x32_bf16(af[0],bq[0],acc[0][0],0,0,0); \
      acc[0][1] = __builtin_amdgcn_mfma_f32_16x16x32_bf16(af[0],bq[1],acc[0][1],0,0,0); \
      acc[1][0] = __builtin_amdgcn_mfma_f32_16x16x32_bf16(af[1],bq[0],acc[1][0],0,0,0); \
      acc[1][1] = __builtin_amdgcn_mfma_f32_16x16x32_bf16(af[1],bq[1],acc[1][1],0,0,0); \
    } }

  // prologue
  BLOAD(0);
  ASTAGE(0, 0);
  BWRITE(0);
  __syncthreads();
  for (int t = 0; t < 15; ++t) {
    const int P = t & 1;
    BLOAD(t + 1);            // issue early (T14)
    ASTAGE(P ^ 1, t + 1);
    COMPUTE(P);              // hides B-load latency
    BWRITE(P ^ 1);
    __syncthreads();
  }
  COMPUTE(1);
  __syncthreads();
#undef BLOAD
#undef BWRITE
#undef ASTAGE
#undef CVT8
#undef COMPUTE

  if (ct < 2) {                                  // Q: row-major, *SCALE folded
    #pragma unroll
    for (int m = 0; m < 2; ++m)
      #pragma unroll
      for (int n = 0; n < 2; ++n) {
        const int col = wc * 32 + n * 16 + l15;
        const float bv = bias[bofs + col];
        #pragma unroll
        for (int r = 0; r < 4; ++r) {
          const int row = row0 + wr * 32 + m * 16 + l4 * 4 + r;
          Qbf[(size_t)row * EE + g0 + col] =
              (__bf16)((acc[m][n][r] + bv) * SCALE);
        }
      }
  } else {                                       // K/V: transpose via LDS
    __bf16* Tb = (__bf16*)ldsA;                  // [64 cols][64 rows chunkXOR]
    #pragma unroll
    for (int m = 0; m < 2; ++m)
      #pragma unroll
      for (int n = 0; n < 2; ++n) {
        const int tc = wc * 32 + n * 16 + l15;
        const float bv = bias[bofs + tc];
        #pragma unroll
        for (int r = 0; r < 4; ++r) {
          const int rl = wr * 32 + m * 16 + l4 * 4 + r;
          Tb[tc * 64 + (((rl >> 3) ^ (tc & 7)) << 3) + (rl & 7)] =
              (__bf16)(acc[m][n][r] + bv);
        }
      }
    __syncthreads();
    const int col = tid >> 2, p2 = tid & 3;      // 64 cols x 4 thr
    const int b = row0 >> 12, s0 = row0 & 4095;
    __bf16* dst = (ct < 4)
        ? &KT[((size_t)b * EE + (ct - 2) * 64 + col) * SS + s0]
        : &VT[((size_t)b * EE + (ct - 4) * 64 + col) * SS + s0];
    #pragma unroll
    for (int j = 0; j < 2; ++j) {
      const int ch = p2 * 2 + j;                 // 8 chunks of 8 bf16
      bf16x8 v = *(const bf16x8*)&Tb[col * 64 + ((ch ^ (col & 7)) << 3)];
      *(bf16x8*)&dst[ch * 8] = v;
    }
  }
}

// ---------------------------------------------------------------------------
// K2: partial K^T V.  grid (64 s-chunks, 2 f-halves, 2 b) x 256 thr.
// ---------------------------------------------------------------------------
__global__ __launch_bounds__(256) void ktv_kernel(
    const __bf16* __restrict__ KT, const __bf16* __restrict__ VT,
    float* __restrict__ part)
{
  const int c = blockIdx.x, fh = blockIdx.y, b = blockIdx.z;
  const int tid = threadIdx.x;
  const int w = tid >> 6, lane = tid & 63;
  const int l15 = lane & 15, l4 = lane >> 4;
  const int s0 = c * 64;
  const int fbase = fh * 64 + w * 16;
  const __bf16* Kb = KT + (size_t)b * EE * SS;
  const __bf16* Vb = VT + (size_t)b * EE * SS;

  f32x4 acc[8] = {};
  #pragma unroll
  for (int ks = 0; ks < 2; ++ks) {
    const int s = s0 + ks * 32 + 8 * l4;
    bf16x8 bv = *(const bf16x8*)&Vb[(size_t)(fbase + l15) * SS + s];
    #pragma unroll
    for (int i = 0; i < 8; ++i) {
      bf16x8 av = *(const bf16x8*)&Kb[(size_t)(i * 16 + l15) * SS + s];
      acc[i] = __builtin_amdgcn_mfma_f32_16x16x32_bf16(av, bv, acc[i], 0, 0, 0);
    }
  }
  float* P = part + (size_t)(b * 64 + c) * 16384;
  #pragma unroll
  for (int i = 0; i < 8; ++i)
    #pragma unroll
    for (int r = 0; r < 4; ++r) {
      int e = i * 16 + l4 * 4 + r;
      int f = fbase + l15;
      P[e * 128 + f] = acc[i][r];
    }
}

// ---------------------------------------------------------------------------
// K3: reduce 64 partials -> MT[b][f][e] = sum (scale folded into Qbf).
// ---------------------------------------------------------------------------
__global__ __launch_bounds__(256) void reduce_kernel(
    const float* __restrict__ part, __bf16* __restrict__ MT)
{
  const int b = blockIdx.y;
  const int e = blockIdx.x * 2 + (threadIdx.x >> 7);
  const int f = threadIdx.x & 127;
  float s = 0.f;
  for (int cc = 0; cc < 64; ++cc)
    s += part[(size_t)(b * 64 + cc) * 16384 + e * 128 + f];
  MT[((size_t)b * EE + f) * EE + e] = (__bf16)s;
}

// ---------------------------------------------------------------------------
// K4: O = Q * M  (MT[f][e]).  grid (128, 2) x 128 thr.
// ---------------------------------------------------------------------------
__global__ __launch_bounds__(128) void qm_kernel(
    const __bf16* __restrict__ Qbf, const __bf16* __restrict__ MT,
    float* __restrict__ out)
{
  const int b = blockIdx.y;
  const int tid = threadIdx.x;
  const int w = tid >> 6, lane = tid & 63;
  const int l15 = lane & 15, l4 = lane >> 4;
  const int row0 = blockIdx.x * 32 + w * 16;
  const __bf16* Qb = Qbf + (size_t)b * SS * EE;
  const __bf16* Mb = MT + (size_t)b * EE * EE;

  f32x4 acc[8] = {};
  #pragma unroll
  for (int ks = 0; ks < 4; ++ks) {
    const int e = ks * 32 + 8 * l4;
    bf16x8 av = *(const bf16x8*)&Qb[(size_t)(row0 + l15) * EE + e];
    #pragma unroll
    for (int j = 0; j < 8; ++j) {
      bf16x8 bv = *(const bf16x8*)&Mb[(size_t)(j * 16 + l15) * EE + e];
      acc[j] = __builtin_amdgcn_mfma_f32_16x16x32_bf16(av, bv, acc[j], 0, 0, 0);
    }
  }
  #pragma unroll
  for (int j = 0; j < 8; ++j)
    #pragma unroll
    for (int r = 0; r < 4; ++r) {
      int srow = row0 + l4 * 4 + r;
      int f = j * 16 + l15;
      out[((size_t)b * SS + srow) * EE + f] = acc[j][r];
    }
}

extern "C" void kernel_launch(void* const* d_in, const int* in_sizes, int n_in,
                              void* d_out, int out_size, void* d_ws, size_t ws_size,
                              hipStream_t stream) {
  const float* x  = (const float*)d_in[0];
  const float* qW = (const float*)d_in[1];
  const float* qB = (const float*)d_in[2];
  const float* kW = (const float*)d_in[3];
  const float* kB = (const float*)d_in[4];
  const float* vW = (const float*)d_in[5];
  const float* vB = (const float*)d_in[6];
  float* out = (float*)d_out;

  char* base = (char*)d_ws;
  __bf16* Qbf = (__bf16*)(base);                         // 2 MB
  __bf16* KT  = (__bf16*)(base + (2u  << 20));           // 2 MB
  __bf16* VT  = (__bf16*)(base + (4u  << 20));           // 2 MB
  float*  part= (float*) (base + (6u  << 20));           // 8 MB
  __bf16* MT  = (__bf16*)(base + (14u << 20));           // 64 KB

  proj_kernel  <<<dim3(768),      256, 0, stream>>>(x, qW, qB, kW, kB, vW, vB,
                                                    Qbf, KT, VT);
  ktv_kernel   <<<dim3(64, 2, 2), 256, 0, stream>>>(KT, VT, part);
  reduce_kernel<<<dim3(64, 2),    256, 0, stream>>>(part, MT);
  qm_kernel    <<<dim3(128, 2),   128, 0, stream>>>(Qbf, MT, out);
}